// Round 16
// baseline (403.295 us; speedup 1.0000x reference)
//
#include <hip/hip_runtime.h>
#include <hip/hip_bf16.h>

typedef unsigned short u16;
typedef unsigned int u32;
typedef short bf16x8 __attribute__((ext_vector_type(8)));
typedef float floatx4 __attribute__((ext_vector_type(4)));

#define CTX 2048
#define HEADSZ 64
#define NHEAD 16
#define DMODEL 1024
#define DFF 4096
#define MROWS 8192  // B*T
#define C_SCALE 0.18033688011112042f  // 0.125 * log2(e)

__device__ __forceinline__ u16 f2b(float f) {
  union { float f; u32 i; } x; x.f = f;
  u32 i = x.i;
  return (u16)((i + 0x7fffu + ((i >> 16) & 1u)) >> 16);  // RNE
}
__device__ __forceinline__ u32 pack2(float a, float b) {
  return (u32)f2b(a) | ((u32)f2b(b) << 16);
}
__device__ __forceinline__ u32 cvtpk(float a, float b) {
  u32 r;
  asm("v_cvt_pk_bf16_f32 %0, %1, %2" : "=v"(r) : "v"(a), "v"(b));
  return r;
}
// native v_exp_f32 (no OCML range fix-up wrapper)
__device__ __forceinline__ float ex2(float x) {
#if __has_builtin(__builtin_amdgcn_exp2f)
  return __builtin_amdgcn_exp2f(x);
#else
  float r;
  asm("v_exp_f32 %0, %1" : "=v"(r) : "v"(x));
  return r;
#endif
}

__device__ __forceinline__ void gl2lds16(const u16* g, u16* l) {
  __builtin_amdgcn_global_load_lds(
      (const __attribute__((address_space(1))) void*)g,
      (__attribute__((address_space(3))) void*)l, 16, 0, 0);
}

// =============================================================================
// prep: ONE launch for all input conditioning (launch-count reduction):
//   blocks [0,8192)      : x fp32 -> bf16 (xb)
//   blocks [8192,12288)  : W1 fp32 -> bf16 (W1b)
//   blocks [12288,15360) : per-head transpose Wq/Wk/Wv -> Wqkvt
//   blocks [15360,19456) : transpose W2 [4096][1024] -> W2t [1024][4096]
//   blocks [19456,19460) : bfv[n] = b2[n] + sum_f b1[f] * W2[f][n]
// =============================================================================
__global__ __launch_bounds__(256) void prep(
    const float* __restrict__ x, u16* __restrict__ xb,
    const float* __restrict__ W1, u16* __restrict__ w1b,
    const float* __restrict__ Wq, const float* __restrict__ Wk,
    const float* __restrict__ Wv, u16* __restrict__ wqkvt,
    const float* __restrict__ W2, u16* __restrict__ w2t,
    const float* __restrict__ b1, const float* __restrict__ b2,
    float* __restrict__ bfv) {
  __shared__ u16 tile[32][33];
  const int b = blockIdx.x;
  const int tid = threadIdx.x;
  if (b < 8192) {
    int i = b * 1024 + tid * 4;
    float4 v = *(const float4*)(x + i);
    *(uint2*)(xb + i) = make_uint2(pack2(v.x, v.y), pack2(v.z, v.w));
  } else if (b < 12288) {
    int j = (b - 8192) * 1024 + tid * 4;
    float4 v = *(const float4*)(W1 + j);
    *(uint2*)(w1b + j) = make_uint2(pack2(v.x, v.y), pack2(v.z, v.w));
  } else if (b < 15360) {
    int bb = b - 12288;
    int bx = bb & 1, by = (bb >> 1) & 31, z = bb >> 6;  // z in [0,48)
    int sec = z >> 4, hh = z & 15;
    const float* ip = (sec == 0 ? Wq : sec == 1 ? Wk : Wv) + (size_t)hh * 65536;
    u16* op = wqkvt + (size_t)(sec * 16 + hh) * 65536;
    int c0 = bx * 32, r0 = by * 32;
    int tx = tid & 31, ty = tid >> 5;
#pragma unroll
    for (int i = 0; i < 32; i += 8)
      tile[ty + i][tx] = f2b(ip[(size_t)(r0 + ty + i) * 64 + (c0 + tx)]);
    __syncthreads();
#pragma unroll
    for (int i = 0; i < 32; i += 8)
      op[(size_t)(c0 + ty + i) * 1024 + (r0 + tx)] = tile[tx][ty + i];
  } else if (b < 19456) {
    int bb = b - 15360;
    int bx = bb & 31, by = bb >> 5;  // by in [0,128)
    int c0 = bx * 32, r0 = by * 32;
    int tx = tid & 31, ty = tid >> 5;
#pragma unroll
    for (int i = 0; i < 32; i += 8)
      tile[ty + i][tx] = f2b(W2[(size_t)(r0 + ty + i) * 1024 + (c0 + tx)]);
    __syncthreads();
#pragma unroll
    for (int i = 0; i < 32; i += 8)
      w2t[(size_t)(c0 + ty + i) * 4096 + (r0 + tx)] = tile[tx][ty + i];
  } else {
    int n = (b - 19456) * 256 + tid;
    float s = b2[n];
    for (int f = 0; f < 4096; f++) s += b1[f] * W2[(size_t)f * 1024 + n];
    bfv[n] = s;
  }
}

// =============================================================================
// 128x256 GEMM (R14/15 verified): BK=32, double-buffered LDS, 64KB -> 2 blk/CU.
// Per K-tile: stage(t+1) 3 loads/thread -> vmcnt(3) -> barrier -> 8 ds_read
// -> lgkm0 -> 16 MFMA -> barrier.
//   MODE 0: blocks [0,768): QKV (q prescaled C_SCALE / k scatter + v transp.)
//           blocks [768,896): Wf = W1@W2 split-K=4 partials (A2/B2t/o3v)
//   MODE 2: f32 relu(acc + bias)   (fused FFN: 256 wg)
// =============================================================================
template <int MODE>
__global__ __launch_bounds__(512, 4) void gemm128(
    const u16* __restrict__ A, const u16* __restrict__ Bt,
    const float* __restrict__ bias,
    void* __restrict__ o0v, void* __restrict__ o1v, void* __restrict__ o2v,
    int N, int Klen, int Kstride,
    const u16* __restrict__ A2, const u16* __restrict__ B2t,
    void* __restrict__ o3v) {
  __shared__ __align__(16) u16 SH[32768];  // 64KB total
  const int tid = threadIdx.x;
  const int quad = (tid >> 4) & 3, l15 = tid & 15;
  const int wave = tid >> 6;
  const int wr = wave >> 2, wc = wave & 3;

  const int id = blockIdx.x;
  const bool wf = (MODE == 0) && (id >= 768);
  const int id2 = id - 768;
  int blockM, blockN, koff, Kl, Ks;
  const u16* Ap;
  const u16* Btp;
  if (wf) {
    blockM = (id2 & 7) << 7;            // 8 M-tiles (M=1024)
    blockN = ((id2 >> 3) & 3) << 8;     // 4 N-tiles (N=1024)
    koff = (id2 >> 5) << 10;            // split * 1024
    Kl = 1024; Ks = 4096;
    Ap = A2; Btp = B2t;
  } else {
    blockM = (((id & 7) << 3) | ((id >> 3) & 7)) << 7;  // 64 M-tiles
    blockN = (id >> 6) << 8;
    koff = 0;
    Kl = Klen; Ks = Kstride;
    Ap = A; Btp = Bt;
  }

  // staging pointers: chunk tid (A), chunks tid / 512+tid (B)
  const int crow = tid >> 2;
  const int cslot = (tid & 3) ^ (crow & 3);
  const u16* ap  = Ap + (size_t)(blockM + crow) * Ks + koff + cslot * 8;
  const u16* bp0 = Btp + (size_t)(blockN + crow) * Ks + koff + cslot * 8;
  const u16* bp1 = bp0 + (size_t)128 * Ks;   // row+128, same slot

  floatx4 acc[4][4];
#pragma unroll
  for (int i = 0; i < 4; i++)
#pragma unroll
    for (int j = 0; j < 4; j++) acc[i][j] = (floatx4){0.f, 0.f, 0.f, 0.f};

  const int nk = Kl >> 5;  // BK=32

  // prologue: stage tile 0 into buf 0
  gl2lds16(ap, SH + tid * 8);
  gl2lds16(bp0, SH + 8192 + tid * 8);
  gl2lds16(bp1, SH + 8192 + 4096 + tid * 8);
  ap += 32; bp0 += 32; bp1 += 32;

  // frag read offsets (bytes): row*64 + (quad^(l15&3))*16
  const int aoff = (wr * 64 + l15) * 64 + ((quad ^ (l15 & 3)) << 4);
  const int boff = (wc * 64 + l15) * 64 + ((quad ^ (l15 & 3)) << 4);

#pragma unroll 1
  for (int t = 0; t < nk; t++) {
    const int cur = t & 1, nxt = cur ^ 1;
    if (t + 1 < nk) {
      u16* An = SH + nxt * 4096;
      u16* Bn = SH + 8192 + nxt * 8192;
      gl2lds16(ap, An + tid * 8);
      gl2lds16(bp0, Bn + tid * 8);
      gl2lds16(bp1, Bn + 4096 + tid * 8);
      ap += 32; bp0 += 32; bp1 += 32;
      asm volatile("s_waitcnt vmcnt(3)" ::: "memory");  // tile t landed
    } else {
      asm volatile("s_waitcnt vmcnt(0)" ::: "memory");
    }
    __builtin_amdgcn_s_barrier();
    const char* ab = (const char*)(SH + cur * 4096);
    const char* bb = (const char*)(SH + 8192 + cur * 8192);
    bf16x8 ar[4], br[4];
#pragma unroll
    for (int mf = 0; mf < 4; mf++)
      ar[mf] = *(const bf16x8*)(ab + mf * 1024 + aoff);
#pragma unroll
    for (int nf = 0; nf < 4; nf++)
      br[nf] = *(const bf16x8*)(bb + nf * 1024 + boff);
    asm volatile("s_waitcnt lgkmcnt(0)" ::: "memory");
    __builtin_amdgcn_s_setprio(1);
#pragma unroll
    for (int mf = 0; mf < 4; mf++)
#pragma unroll
      for (int nf = 0; nf < 4; nf++)
        acc[mf][nf] = __builtin_amdgcn_mfma_f32_16x16x32_bf16(ar[mf], br[nf], acc[mf][nf], 0, 0, 0);
    __builtin_amdgcn_s_setprio(0);
    __builtin_amdgcn_s_barrier();  // reads of buf[cur] done
  }

  const int m0 = blockM + wr * 64 + quad * 4;
  const int n0 = blockN + wc * 64 + l15;
  if (MODE == 0 && !wf) {
    u16* o0 = (u16*)o0v; u16* o1 = (u16*)o1v; u16* o2 = (u16*)o2v;
    const int lane = tid & 63;
    const int n0w = blockN + wc * 64;
    const int sec = n0w >> 10, hh = (n0w >> 6) & 15;
    const int m0w = blockM + wr * 64;
    const int b = m0w >> 11, t0 = m0w & 2047;
    const int lr = lane >> 3, lc = lane & 7;
    u16* buf = SH + wave * 4096;  // wave-private 8KB scratch
    if (sec < 2) {
      // q/k: row-major coalesced scatter; q prescaled by C_SCALE.
      u16* dst = (sec == 0) ? o0 : o1;
      const float scl = (sec == 0) ? C_SCALE : 1.0f;
#pragma unroll
      for (int nf = 0; nf < 4; nf++)
#pragma unroll
        for (int mf = 0; mf < 4; mf++)
#pragma unroll
          for (int r = 0; r < 4; r++) {
            int row = mf * 16 + quad * 4 + r;
            int col2 = (nf * 16 + l15) ^ ((row & 7) << 3);
            buf[row * 64 + col2] = f2b(acc[mf][nf][r] * scl);
          }
      u16* base = dst + ((size_t)((b * 16 + hh) * 2048 + t0)) * 64 + lc * 8;
#pragma unroll
      for (int i = 0; i < 8; i++) {
        int row = i * 8 + lr;
        uint4 v = *(const uint4*)(buf + row * 64 + ((lc ^ lr) << 3));
        *(uint4*)(base + (size_t)row * 64) = v;
      }
    } else {
      // v: stage TRANSPOSED [d][t]; store d-rows as 128B-contiguous runs.
      u16* dstv = o2 + ((size_t)((b * 16 + hh) * 64)) * CTX + t0;
#pragma unroll
      for (int nf = 0; nf < 4; nf++)
#pragma unroll
        for (int mf = 0; mf < 4; mf++) {
          int dr = nf * 16 + l15;
          int tc = (mf * 16 + quad * 4) ^ ((dr & 7) << 3);
          *(uint2*)&buf[dr * 64 + tc] = make_uint2(
              pack2(acc[mf][nf][0], acc[mf][nf][1]),
              pack2(acc[mf][nf][2], acc[mf][nf][3]));
        }
#pragma unroll
      for (int i = 0; i < 8; i++) {
        int dr = i * 8 + lr;
        uint4 v = *(const uint4*)&buf[dr * 64 + ((lc * 8) ^ ((dr & 7) << 3))];
        *(uint4*)(dstv + (size_t)dr * CTX + lc * 8) = v;
      }
    }
  } else if (MODE == 0) {
    // Wf split-K partial store (split = id2>>5); N=1024
    float* o3 = (float*)o3v + ((size_t)(id2 >> 5) << 20);
#pragma unroll
    for (int nf = 0; nf < 4; nf++) {
      int n = n0 + nf * 16;
#pragma unroll
      for (int mf = 0; mf < 4; mf++)
#pragma unroll
        for (int r = 0; r < 4; r++) {
          int m = m0 + mf * 16 + r;
          o3[(size_t)m * 1024 + n] = acc[mf][nf][r];
        }
    }
  } else {
    float* o0 = (float*)o0v;
#pragma unroll
    for (int nf = 0; nf < 4; nf++) {
      int n = n0 + nf * 16;
      float bv = bias[n];
#pragma unroll
      for (int mf = 0; mf < 4; mf++)
#pragma unroll
        for (int r = 0; r < 4; r++) {
          int m = m0 + mf * 16 + r;
          float v = acc[mf][nf][r] + bv;
          o0[(size_t)m * N + n] = v > 0.f ? v : 0.f;
        }
    }
  }
}

// =============================================================================
// MFMA causal flash attention (R15 verified: prescaled Q, fixed-max native-exp2
// softmax, ones-trick row-sum, setprio) + Wf split-K REDUCTION on grid row
// y==16 (64 blocks; Wft consumed only by the next kernel).
// Grid (64 bh, 17): y<16 attn with j=15-y longest-first; y==16 reduce.
// =============================================================================
__global__ __launch_bounds__(256) void attn_mfma(
    const u16* __restrict__ Q, const u16* __restrict__ K,
    const u16* __restrict__ Vt, u16* __restrict__ out,
    const float* __restrict__ partials, u16* __restrict__ wft) {
  __shared__ __align__(16) u16 Kbuf[2][4096];
  __shared__ __align__(16) u16 Vbuf[2][4096];
  __shared__ __align__(16) u16 Plds[4][32][72];
  const int tid = threadIdx.x;
  if (blockIdx.y == 16) {
    // Wf reduction: 64 blocks x 256 thr x 16 iters x float4
    int off = blockIdx.x * 16384;
#pragma unroll 1
    for (int it = 0; it < 16; it++) {
      int i = off + (it * 256 + tid) * 4;
      float4 s = *(const float4*)(partials + i);
#pragma unroll
      for (int sp = 1; sp < 4; sp++) {
        float4 v = *(const float4*)(partials + ((size_t)sp << 20) + i);
        s.x += v.x; s.y += v.y; s.z += v.z; s.w += v.w;
      }
      *(uint2*)(wft + i) = make_uint2(pack2(s.x, s.y), pack2(s.z, s.w));
    }
    return;
  }
  const int wave = tid >> 6, lane = tid & 63;
  const int quad = lane >> 4, l15 = lane & 15;
  const int sx = l15 & 7;
  const int bh = blockIdx.x;
  const int j = 15 - blockIdx.y;      // longest-first
  const size_t qkb = (size_t)bh * CTX * 64;
  const size_t vb = (size_t)bh * 64 * CTX;

  const int ch0 = wave * 64 + lane;
  const int ch1 = 256 + ch0;
  const int r0 = ch0 >> 3, s0 = (ch0 & 7) ^ (r0 & 7);
  const int r1 = ch1 >> 3, s1 = (ch1 & 7) ^ (r1 & 7);
  const u16* kg0 = K + qkb + r0 * 64 + s0 * 8;
  const u16* kg1 = K + qkb + r1 * 64 + s1 * 8;
  const u16* vg0 = Vt + vb + (size_t)r0 * CTX + s0 * 8;
  const u16* vg1 = Vt + vb + (size_t)r1 * CTX + s1 * 8;

  const int qbase = j * 128 + wave * 32;
  const int NST = 2 * j + 2;
  const int nstw = 2 * j + (wave >> 1) + 1;

  bf16x8 qf[2][2];
#pragma unroll
  for (int mt = 0; mt < 2; mt++)
#pragma unroll
    for (int kc = 0; kc < 2; kc++)
      qf[mt][kc] = *(const bf16x8*)(Q + qkb + (size_t)(qbase + mt * 16 + l15) * 64 + kc * 32 + quad * 8);

  bf16x8 ones;
#pragma unroll
  for (int i = 0; i < 8; i++) ones[i] = (short)0x3F80;  // bf16 1.0

  floatx4 o[2][4];
#pragma unroll
  for (int mt = 0; mt < 2; mt++)
#pragma unroll
    for (int dt = 0; dt < 4; dt++) o[mt][dt] = (floatx4){0.f, 0.f, 0.f, 0.f};
  floatx4 lacc[2];
  lacc[0] = (floatx4){0.f, 0.f, 0.f, 0.f};
  lacc[1] = (floatx4){0.f, 0.f, 0.f, 0.f};

  gl2lds16(kg0, &Kbuf[0][wave * 512]);
  gl2lds16(kg1, &Kbuf[0][2048 + wave * 512]);
  gl2lds16(vg0, &Vbuf[0][wave * 512]);
  gl2lds16(vg1, &Vbuf[0][2048 + wave * 512]);

#pragma unroll 1
  for (int st = 0; st < NST; st++) {
    __syncthreads();
    if (st + 1 < NST) {
      const int sb = (st + 1) * 64;
      const int b = (st + 1) & 1;
      gl2lds16(kg0 + sb * 64, &Kbuf[b][wave * 512]);
      gl2lds16(kg1 + sb * 64, &Kbuf[b][2048 + wave * 512]);
      gl2lds16(vg0 + sb, &Vbuf[b][wave * 512]);
      gl2lds16(vg1 + sb, &Vbuf[b][2048 + wave * 512]);
    }
    if (st >= nstw) continue;
    const int sbase = st * 64;
    const u16* kb = Kbuf[st & 1];
    const u16* vv = Vbuf[st & 1];

    floatx4 stf[2][4];
    __builtin_amdgcn_s_setprio(1);
#pragma unroll
    for (int sc = 0; sc < 4; sc++) {
      const bf16x8* kr = (const bf16x8*)(kb + (sc * 16 + l15) * 64);
      bf16x8 k0 = kr[quad ^ sx];
      bf16x8 k1 = kr[(4 + quad) ^ sx];
#pragma unroll
      for (int mt = 0; mt < 2; mt++) {
        floatx4 z = (floatx4){0.f, 0.f, 0.f, 0.f};
        z = __builtin_amdgcn_mfma_f32_16x16x32_bf16(k0, qf[mt][0], z, 0, 0, 0);
        stf[mt][sc] = __builtin_amdgcn_mfma_f32_16x16x32_bf16(k1, qf[mt][1], z, 0, 0, 0);
      }
    }
    __builtin_amdgcn_s_setprio(0);
    if (st == nstw - 1) {
#pragma unroll
      for (int mt = 0; mt < 2; mt++) {
        int qq = qbase + mt * 16 + l15;
#pragma unroll
        for (int sc = 0; sc < 4; sc++)
#pragma unroll
          for (int r = 0; r < 4; r++) {
            int s = sbase + sc * 16 + quad * 4 + r;
            if (s > qq) stf[mt][sc][r] = -1e30f;
          }
      }
    }
    // Fixed-max softmax with prescaled Q: p = exp2(s). Masked s=-1e30 -> p=0.
#pragma unroll
    for (int mt = 0; mt < 2; mt++) {
#pragma unroll
      for (int sc = 0; sc < 4; sc++) {
        floatx4 s4 = stf[mt][sc];
        float p0 = ex2(s4[0]);
        float p1 = ex2(s4[1]);
        float p2 = ex2(s4[2]);
        float p3 = ex2(s4[3]);
        *(uint2*)&Plds[wave][mt * 16 + l15][sc * 16 + quad * 4] =
            make_uint2(cvtpk(p0, p1), cvtpk(p2, p3));
      }
    }
    asm volatile("s_waitcnt lgkmcnt(0)" ::: "memory");
    __builtin_amdgcn_s_setprio(1);
#pragma unroll
    for (int sc2 = 0; sc2 < 2; sc2++) {
      bf16x8 pf[2];
#pragma unroll
      for (int mt = 0; mt < 2; mt++)
        pf[mt] = *(const bf16x8*)&Plds[wave][mt * 16 + l15][sc2 * 32 + quad * 8];
#pragma unroll
      for (int mt = 0; mt < 2; mt++)
        lacc[mt] = __builtin_amdgcn_mfma_f32_16x16x32_bf16(ones, pf[mt], lacc[mt], 0, 0, 0);
#pragma unroll
      for (int dt = 0; dt < 4; dt++) {
        const bf16x8* vr = (const bf16x8*)(vv + (dt * 16 + l15) * 64);
        bf16x8 vf = vr[(sc2 * 4 + quad) ^ sx];
#pragma unroll
        for (int mt = 0; mt < 2; mt++)
          o[mt][dt] = __builtin_amdgcn_mfma_f32_16x16x32_bf16(vf, pf[mt], o[mt][dt], 0, 0, 0);
      }
    }
    __builtin_amdgcn_s_setprio(0);
  }

#pragma unroll
  for (int mt = 0; mt < 2; mt++) {
    float inv = 1.0f / lacc[mt][0];  // every lane's reg0 = full row sum
    int row = (bh >> 4) * CTX + qbase + mt * 16 + l15;
    u16* orow = out + (size_t)row * DMODEL + (bh & 15) * 64;
#pragma unroll
    for (int dt = 0; dt < 4; dt++) {
      floatx4 v = o[mt][dt];
      *(u32*)(orow + dt * 16 + quad * 4) = cvtpk(v[0] * inv, v[1] * inv);
      *(u32*)(orow + dt * 16 + quad * 4 + 2) = cvtpk(v[2] * inv, v[3] * inv);
    }
  }
}

extern "C" void kernel_launch(void* const* d_in, const int* in_sizes, int n_in,
                              void* d_out, int out_size, void* d_ws, size_t ws_size,
                              hipStream_t stream) {
  const float* x  = (const float*)d_in[0];
  const float* Wq = (const float*)d_in[1];
  const float* Wk = (const float*)d_in[2];
  const float* Wv = (const float*)d_in[3];
  const float* W1 = (const float*)d_in[4];
  const float* b1 = (const float*)d_in[5];
  const float* W2 = (const float*)d_in[6];
  const float* b2 = (const float*)d_in[7];
  float* out = (float*)d_out;

  u16* ws    = (u16*)d_ws;
  u16* W2t   = ws;                              // [1024][4096]  8 MB
  u16* W1b   = W2t + (size_t)1024 * 4096;       // [1024][4096]  8 MB (bf16 W1)
  u16* Wft   = W1b + (size_t)1024 * 4096;       // [1024][1024]  2 MB
  float* bfv = (float*)(Wft + (size_t)1024 * 1024);  // [1024] f32
  u16* xb    = Wft + (size_t)1024 * 1024 + 4096;     // [8192][1024] 16 MB
  u16* Wqkvt = xb + (size_t)MROWS * 1024;       // [3072][1024]  6 MB
  u16* q     = Wqkvt + (size_t)3072 * 1024;     // [B*H][T][64] 16 MB
  u16* k     = q + (size_t)MROWS * 1024;        // [B*H][T][64] 16 MB
  u16* vt    = k + (size_t)MROWS * 1024;        // [B*H][64][T] 16 MB
  float* partials = (float*)(vt + (size_t)MROWS * 1024);  // [4][1M] f32 16 MB
  u16* att   = xb;                              // att aliases xb (dead post-QKV)

  // 1) all input conditioning + fused bias (bfv = b1@W2 + b2) in ONE launch
  prep<<<19460, 256, 0, stream>>>(x, xb, W1, W1b, Wq, Wk, Wv, Wqkvt,
                                  W2, W2t, b1, b2, bfv);
  // 2) QKV (blocks 0-767) + Wf split-K partials (blocks 768-895) in ONE launch
  gemm128<0><<<896, 512, 0, stream>>>(xb, Wqkvt, nullptr, q, k, vt,
                                      3072, 1024, 1024, W2t, W1b, partials);
  // 3) attention (y<16) + Wf reduction (y==16) in ONE launch
  attn_mfma<<<dim3(64, 17), 256, 0, stream>>>(q, k, vt, att, partials, Wft);
  // 4) fused FFN: out = relu(att @ Wf + bfv)
  gemm128<2><<<256, 512, 0, stream>>>(att, Wft, bfv, out, nullptr, nullptr,
                                      1024, 1024, 1024, nullptr, nullptr, nullptr);
}

// Round 17
// 289.101 us; speedup vs baseline: 1.3950x; 1.3950x over previous
//
#include <hip/hip_runtime.h>
#include <hip/hip_bf16.h>

typedef unsigned short u16;
typedef unsigned int u32;
typedef short bf16x8 __attribute__((ext_vector_type(8)));
typedef float floatx4 __attribute__((ext_vector_type(4)));

#define CTX 2048
#define HEADSZ 64
#define NHEAD 16
#define DMODEL 1024
#define DFF 4096
#define MROWS 8192  // B*T
#define C_SCALE 0.18033688011112042f  // 0.125 * log2(e)

__device__ __forceinline__ u16 f2b(float f) {
  union { float f; u32 i; } x; x.f = f;
  u32 i = x.i;
  return (u16)((i + 0x7fffu + ((i >> 16) & 1u)) >> 16);  // RNE
}
__device__ __forceinline__ u32 pack2(float a, float b) {
  return (u32)f2b(a) | ((u32)f2b(b) << 16);
}
__device__ __forceinline__ u32 cvtpk(float a, float b) {
  u32 r;
  asm("v_cvt_pk_bf16_f32 %0, %1, %2" : "=v"(r) : "v"(a), "v"(b));
  return r;
}
// native v_exp_f32 (no OCML range fix-up wrapper)
__device__ __forceinline__ float ex2(float x) {
#if __has_builtin(__builtin_amdgcn_exp2f)
  return __builtin_amdgcn_exp2f(x);
#else
  float r;
  asm("v_exp_f32 %0, %1" : "=v"(r) : "v"(x));
  return r;
#endif
}

__device__ __forceinline__ void gl2lds16(const u16* g, u16* l) {
  __builtin_amdgcn_global_load_lds(
      (const __attribute__((address_space(1))) void*)g,
      (__attribute__((address_space(3))) void*)l, 16, 0, 0);
}

// =============================================================================
// prep: ONE launch for all input conditioning:
//   blocks [0,8192)      : x fp32 -> bf16 (xb)
//   blocks [8192,12288)  : W1 fp32 -> bf16 (W1b)
//   blocks [12288,15360) : per-head transpose Wq/Wk/Wv -> Wqkvt
//   blocks [15360,19456) : transpose W2 [4096][1024] -> W2t [1024][4096]
//   blocks [19456,19584) : bfp[fc][n] = sum_{f in chunk fc} b1[f]*W2[f][n]
//     (R17 fix: 128 parallel partial blocks -- the R16 4-block 4096-iteration
//      serial loop was the 164us laggard; final reduce rides on attn launch.)
// =============================================================================
__global__ __launch_bounds__(256) void prep(
    const float* __restrict__ x, u16* __restrict__ xb,
    const float* __restrict__ W1, u16* __restrict__ w1b,
    const float* __restrict__ Wq, const float* __restrict__ Wk,
    const float* __restrict__ Wv, u16* __restrict__ wqkvt,
    const float* __restrict__ W2, u16* __restrict__ w2t,
    const float* __restrict__ b1, float* __restrict__ bfp) {
  __shared__ u16 tile[32][33];
  const int b = blockIdx.x;
  const int tid = threadIdx.x;
  if (b < 8192) {
    int i = b * 1024 + tid * 4;
    float4 v = *(const float4*)(x + i);
    *(uint2*)(xb + i) = make_uint2(pack2(v.x, v.y), pack2(v.z, v.w));
  } else if (b < 12288) {
    int j = (b - 8192) * 1024 + tid * 4;
    float4 v = *(const float4*)(W1 + j);
    *(uint2*)(w1b + j) = make_uint2(pack2(v.x, v.y), pack2(v.z, v.w));
  } else if (b < 15360) {
    int bb = b - 12288;
    int bx = bb & 1, by = (bb >> 1) & 31, z = bb >> 6;  // z in [0,48)
    int sec = z >> 4, hh = z & 15;
    const float* ip = (sec == 0 ? Wq : sec == 1 ? Wk : Wv) + (size_t)hh * 65536;
    u16* op = wqkvt + (size_t)(sec * 16 + hh) * 65536;
    int c0 = bx * 32, r0 = by * 32;
    int tx = tid & 31, ty = tid >> 5;
#pragma unroll
    for (int i = 0; i < 32; i += 8)
      tile[ty + i][tx] = f2b(ip[(size_t)(r0 + ty + i) * 64 + (c0 + tx)]);
    __syncthreads();
#pragma unroll
    for (int i = 0; i < 32; i += 8)
      op[(size_t)(c0 + ty + i) * 1024 + (r0 + tx)] = tile[tx][ty + i];
  } else if (b < 19456) {
    int bb = b - 15360;
    int bx = bb & 31, by = bb >> 5;  // by in [0,128)
    int c0 = bx * 32, r0 = by * 32;
    int tx = tid & 31, ty = tid >> 5;
#pragma unroll
    for (int i = 0; i < 32; i += 8)
      tile[ty + i][tx] = f2b(W2[(size_t)(r0 + ty + i) * 1024 + (c0 + tx)]);
    __syncthreads();
#pragma unroll
    for (int i = 0; i < 32; i += 8)
      w2t[(size_t)(c0 + ty + i) * 4096 + (r0 + tx)] = tile[tx][ty + i];
  } else {
    int bb = b - 19456;            // 0..127
    int fc = bb >> 2, nc = bb & 3; // 32 f-chunks x 4 n-chunks
    int n = nc * 256 + tid;
    int f0 = fc * 128;
    float s = 0.f;
#pragma unroll 8
    for (int f = 0; f < 128; f++)
      s += b1[f0 + f] * W2[(size_t)(f0 + f) * 1024 + n];
    bfp[fc * 1024 + n] = s;
  }
}

// =============================================================================
// 128x256 GEMM (R14/15 verified): BK=32, double-buffered LDS, 64KB -> 2 blk/CU.
//   MODE 0: blocks [0,768): QKV (q prescaled C_SCALE / k scatter + v transp.)
//           blocks [768,896): Wf = W1@W2 split-K=4 partials (A2/B2t/o3v)
//   MODE 2: f32 relu(acc + bias)   (fused FFN: 256 wg)
// =============================================================================
template <int MODE>
__global__ __launch_bounds__(512, 4) void gemm128(
    const u16* __restrict__ A, const u16* __restrict__ Bt,
    const float* __restrict__ bias,
    void* __restrict__ o0v, void* __restrict__ o1v, void* __restrict__ o2v,
    int N, int Klen, int Kstride,
    const u16* __restrict__ A2, const u16* __restrict__ B2t,
    void* __restrict__ o3v) {
  __shared__ __align__(16) u16 SH[32768];  // 64KB total
  const int tid = threadIdx.x;
  const int quad = (tid >> 4) & 3, l15 = tid & 15;
  const int wave = tid >> 6;
  const int wr = wave >> 2, wc = wave & 3;

  const int id = blockIdx.x;
  const bool wf = (MODE == 0) && (id >= 768);
  const int id2 = id - 768;
  int blockM, blockN, koff, Kl, Ks;
  const u16* Ap;
  const u16* Btp;
  if (wf) {
    blockM = (id2 & 7) << 7;            // 8 M-tiles (M=1024)
    blockN = ((id2 >> 3) & 3) << 8;     // 4 N-tiles (N=1024)
    koff = (id2 >> 5) << 10;            // split * 1024
    Kl = 1024; Ks = 4096;
    Ap = A2; Btp = B2t;
  } else {
    blockM = (((id & 7) << 3) | ((id >> 3) & 7)) << 7;  // 64 M-tiles
    blockN = (id >> 6) << 8;
    koff = 0;
    Kl = Klen; Ks = Kstride;
    Ap = A; Btp = Bt;
  }

  // staging pointers: chunk tid (A), chunks tid / 512+tid (B)
  const int crow = tid >> 2;
  const int cslot = (tid & 3) ^ (crow & 3);
  const u16* ap  = Ap + (size_t)(blockM + crow) * Ks + koff + cslot * 8;
  const u16* bp0 = Btp + (size_t)(blockN + crow) * Ks + koff + cslot * 8;
  const u16* bp1 = bp0 + (size_t)128 * Ks;   // row+128, same slot

  floatx4 acc[4][4];
#pragma unroll
  for (int i = 0; i < 4; i++)
#pragma unroll
    for (int j = 0; j < 4; j++) acc[i][j] = (floatx4){0.f, 0.f, 0.f, 0.f};

  const int nk = Kl >> 5;  // BK=32

  // prologue: stage tile 0 into buf 0
  gl2lds16(ap, SH + tid * 8);
  gl2lds16(bp0, SH + 8192 + tid * 8);
  gl2lds16(bp1, SH + 8192 + 4096 + tid * 8);
  ap += 32; bp0 += 32; bp1 += 32;

  // frag read offsets (bytes): row*64 + (quad^(l15&3))*16
  const int aoff = (wr * 64 + l15) * 64 + ((quad ^ (l15 & 3)) << 4);
  const int boff = (wc * 64 + l15) * 64 + ((quad ^ (l15 & 3)) << 4);

#pragma unroll 1
  for (int t = 0; t < nk; t++) {
    const int cur = t & 1, nxt = cur ^ 1;
    if (t + 1 < nk) {
      u16* An = SH + nxt * 4096;
      u16* Bn = SH + 8192 + nxt * 8192;
      gl2lds16(ap, An + tid * 8);
      gl2lds16(bp0, Bn + tid * 8);
      gl2lds16(bp1, Bn + 4096 + tid * 8);
      ap += 32; bp0 += 32; bp1 += 32;
      asm volatile("s_waitcnt vmcnt(3)" ::: "memory");  // tile t landed
    } else {
      asm volatile("s_waitcnt vmcnt(0)" ::: "memory");
    }
    __builtin_amdgcn_s_barrier();
    const char* ab = (const char*)(SH + cur * 4096);
    const char* bb = (const char*)(SH + 8192 + cur * 8192);
    bf16x8 ar[4], br[4];
#pragma unroll
    for (int mf = 0; mf < 4; mf++)
      ar[mf] = *(const bf16x8*)(ab + mf * 1024 + aoff);
#pragma unroll
    for (int nf = 0; nf < 4; nf++)
      br[nf] = *(const bf16x8*)(bb + nf * 1024 + boff);
    asm volatile("s_waitcnt lgkmcnt(0)" ::: "memory");
    __builtin_amdgcn_s_setprio(1);
#pragma unroll
    for (int mf = 0; mf < 4; mf++)
#pragma unroll
      for (int nf = 0; nf < 4; nf++)
        acc[mf][nf] = __builtin_amdgcn_mfma_f32_16x16x32_bf16(ar[mf], br[nf], acc[mf][nf], 0, 0, 0);
    __builtin_amdgcn_s_setprio(0);
    __builtin_amdgcn_s_barrier();  // reads of buf[cur] done
  }

  const int m0 = blockM + wr * 64 + quad * 4;
  const int n0 = blockN + wc * 64 + l15;
  if (MODE == 0 && !wf) {
    u16* o0 = (u16*)o0v; u16* o1 = (u16*)o1v; u16* o2 = (u16*)o2v;
    const int lane = tid & 63;
    const int n0w = blockN + wc * 64;
    const int sec = n0w >> 10, hh = (n0w >> 6) & 15;
    const int m0w = blockM + wr * 64;
    const int b = m0w >> 11, t0 = m0w & 2047;
    const int lr = lane >> 3, lc = lane & 7;
    u16* buf = SH + wave * 4096;  // wave-private 8KB scratch
    if (sec < 2) {
      // q/k: row-major coalesced scatter; q prescaled by C_SCALE.
      u16* dst = (sec == 0) ? o0 : o1;
      const float scl = (sec == 0) ? C_SCALE : 1.0f;
#pragma unroll
      for (int nf = 0; nf < 4; nf++)
#pragma unroll
        for (int mf = 0; mf < 4; mf++)
#pragma unroll
          for (int r = 0; r < 4; r++) {
            int row = mf * 16 + quad * 4 + r;
            int col2 = (nf * 16 + l15) ^ ((row & 7) << 3);
            buf[row * 64 + col2] = f2b(acc[mf][nf][r] * scl);
          }
      u16* base = dst + ((size_t)((b * 16 + hh) * 2048 + t0)) * 64 + lc * 8;
#pragma unroll
      for (int i = 0; i < 8; i++) {
        int row = i * 8 + lr;
        uint4 v = *(const uint4*)(buf + row * 64 + ((lc ^ lr) << 3));
        *(uint4*)(base + (size_t)row * 64) = v;
      }
    } else {
      // v: stage TRANSPOSED [d][t]; store d-rows as 128B-contiguous runs.
      u16* dstv = o2 + ((size_t)((b * 16 + hh) * 64)) * CTX + t0;
#pragma unroll
      for (int nf = 0; nf < 4; nf++)
#pragma unroll
        for (int mf = 0; mf < 4; mf++) {
          int dr = nf * 16 + l15;
          int tc = (mf * 16 + quad * 4) ^ ((dr & 7) << 3);
          *(uint2*)&buf[dr * 64 + tc] = make_uint2(
              pack2(acc[mf][nf][0], acc[mf][nf][1]),
              pack2(acc[mf][nf][2], acc[mf][nf][3]));
        }
#pragma unroll
      for (int i = 0; i < 8; i++) {
        int dr = i * 8 + lr;
        uint4 v = *(const uint4*)&buf[dr * 64 + ((lc * 8) ^ ((dr & 7) << 3))];
        *(uint4*)(dstv + (size_t)dr * CTX + lc * 8) = v;
      }
    }
  } else if (MODE == 0) {
    // Wf split-K partial store (split = id2>>5); N=1024
    float* o3 = (float*)o3v + ((size_t)(id2 >> 5) << 20);
#pragma unroll
    for (int nf = 0; nf < 4; nf++) {
      int n = n0 + nf * 16;
#pragma unroll
      for (int mf = 0; mf < 4; mf++)
#pragma unroll
        for (int r = 0; r < 4; r++) {
          int m = m0 + mf * 16 + r;
          o3[(size_t)m * 1024 + n] = acc[mf][nf][r];
        }
    }
  } else {
    float* o0 = (float*)o0v;
#pragma unroll
    for (int nf = 0; nf < 4; nf++) {
      int n = n0 + nf * 16;
      float bv = bias[n];
#pragma unroll
      for (int mf = 0; mf < 4; mf++)
#pragma unroll
        for (int r = 0; r < 4; r++) {
          int m = m0 + mf * 16 + r;
          float v = acc[mf][nf][r] + bv;
          o0[(size_t)m * N + n] = v > 0.f ? v : 0.f;
        }
    }
  }
}

// =============================================================================
// MFMA causal flash attention (R15 verified) + Wf split-K reduce + bfv reduce
// on grid row y==16.  Grid (64 bh, 17): y<16 attn (j=15-y longest-first);
// y==16: 64 blocks reduce Wft; block x==0 also computes
// bfv[n] = b2[n] + sum_fc bfp[fc][n]  (consumed by next launch).
// =============================================================================
__global__ __launch_bounds__(256) void attn_mfma(
    const u16* __restrict__ Q, const u16* __restrict__ K,
    const u16* __restrict__ Vt, u16* __restrict__ out,
    const float* __restrict__ partials, u16* __restrict__ wft,
    const float* __restrict__ bfp, const float* __restrict__ b2,
    float* __restrict__ bfv) {
  __shared__ __align__(16) u16 Kbuf[2][4096];
  __shared__ __align__(16) u16 Vbuf[2][4096];
  __shared__ __align__(16) u16 Plds[4][32][72];
  const int tid = threadIdx.x;
  if (blockIdx.y == 16) {
    // Wf reduction: 64 blocks x 256 thr x 16 iters x float4
    int off = blockIdx.x * 16384;
#pragma unroll 1
    for (int it = 0; it < 16; it++) {
      int i = off + (it * 256 + tid) * 4;
      float4 s = *(const float4*)(partials + i);
#pragma unroll
      for (int sp = 1; sp < 4; sp++) {
        float4 v = *(const float4*)(partials + ((size_t)sp << 20) + i);
        s.x += v.x; s.y += v.y; s.z += v.z; s.w += v.w;
      }
      *(uint2*)(wft + i) = make_uint2(pack2(s.x, s.y), pack2(s.z, s.w));
    }
    if (blockIdx.x == 0) {
      // bfv reduce: 1024 values, 4 per thread
      int n = tid * 4;
      float4 s = *(const float4*)(b2 + n);
#pragma unroll
      for (int fc = 0; fc < 32; fc++) {
        float4 v = *(const float4*)(bfp + fc * 1024 + n);
        s.x += v.x; s.y += v.y; s.z += v.z; s.w += v.w;
      }
      *(float4*)(bfv + n) = s;
    }
    return;
  }
  const int wave = tid >> 6, lane = tid & 63;
  const int quad = lane >> 4, l15 = lane & 15;
  const int sx = l15 & 7;
  const int bh = blockIdx.x;
  const int j = 15 - blockIdx.y;      // longest-first
  const size_t qkb = (size_t)bh * CTX * 64;
  const size_t vb = (size_t)bh * 64 * CTX;

  const int ch0 = wave * 64 + lane;
  const int ch1 = 256 + ch0;
  const int r0 = ch0 >> 3, s0 = (ch0 & 7) ^ (r0 & 7);
  const int r1 = ch1 >> 3, s1 = (ch1 & 7) ^ (r1 & 7);
  const u16* kg0 = K + qkb + r0 * 64 + s0 * 8;
  const u16* kg1 = K + qkb + r1 * 64 + s1 * 8;
  const u16* vg0 = Vt + vb + (size_t)r0 * CTX + s0 * 8;
  const u16* vg1 = Vt + vb + (size_t)r1 * CTX + s1 * 8;

  const int qbase = j * 128 + wave * 32;
  const int NST = 2 * j + 2;
  const int nstw = 2 * j + (wave >> 1) + 1;

  bf16x8 qf[2][2];
#pragma unroll
  for (int mt = 0; mt < 2; mt++)
#pragma unroll
    for (int kc = 0; kc < 2; kc++)
      qf[mt][kc] = *(const bf16x8*)(Q + qkb + (size_t)(qbase + mt * 16 + l15) * 64 + kc * 32 + quad * 8);

  bf16x8 ones;
#pragma unroll
  for (int i = 0; i < 8; i++) ones[i] = (short)0x3F80;  // bf16 1.0

  floatx4 o[2][4];
#pragma unroll
  for (int mt = 0; mt < 2; mt++)
#pragma unroll
    for (int dt = 0; dt < 4; dt++) o[mt][dt] = (floatx4){0.f, 0.f, 0.f, 0.f};
  floatx4 lacc[2];
  lacc[0] = (floatx4){0.f, 0.f, 0.f, 0.f};
  lacc[1] = (floatx4){0.f, 0.f, 0.f, 0.f};

  gl2lds16(kg0, &Kbuf[0][wave * 512]);
  gl2lds16(kg1, &Kbuf[0][2048 + wave * 512]);
  gl2lds16(vg0, &Vbuf[0][wave * 512]);
  gl2lds16(vg1, &Vbuf[0][2048 + wave * 512]);

#pragma unroll 1
  for (int st = 0; st < NST; st++) {
    __syncthreads();
    if (st + 1 < NST) {
      const int sb = (st + 1) * 64;
      const int b = (st + 1) & 1;
      gl2lds16(kg0 + sb * 64, &Kbuf[b][wave * 512]);
      gl2lds16(kg1 + sb * 64, &Kbuf[b][2048 + wave * 512]);
      gl2lds16(vg0 + sb, &Vbuf[b][wave * 512]);
      gl2lds16(vg1 + sb, &Vbuf[b][2048 + wave * 512]);
    }
    if (st >= nstw) continue;
    const int sbase = st * 64;
    const u16* kb = Kbuf[st & 1];
    const u16* vv = Vbuf[st & 1];

    floatx4 stf[2][4];
    __builtin_amdgcn_s_setprio(1);
#pragma unroll
    for (int sc = 0; sc < 4; sc++) {
      const bf16x8* kr = (const bf16x8*)(kb + (sc * 16 + l15) * 64);
      bf16x8 k0 = kr[quad ^ sx];
      bf16x8 k1 = kr[(4 + quad) ^ sx];
#pragma unroll
      for (int mt = 0; mt < 2; mt++) {
        floatx4 z = (floatx4){0.f, 0.f, 0.f, 0.f};
        z = __builtin_amdgcn_mfma_f32_16x16x32_bf16(k0, qf[mt][0], z, 0, 0, 0);
        stf[mt][sc] = __builtin_amdgcn_mfma_f32_16x16x32_bf16(k1, qf[mt][1], z, 0, 0, 0);
      }
    }
    __builtin_amdgcn_s_setprio(0);
    if (st == nstw - 1) {
#pragma unroll
      for (int mt = 0; mt < 2; mt++) {
        int qq = qbase + mt * 16 + l15;
#pragma unroll
        for (int sc = 0; sc < 4; sc++)
#pragma unroll
          for (int r = 0; r < 4; r++) {
            int s = sbase + sc * 16 + quad * 4 + r;
            if (s > qq) stf[mt][sc][r] = -1e30f;
          }
      }
    }
    // Fixed-max softmax with prescaled Q: p = exp2(s). Masked s=-1e30 -> p=0.
#pragma unroll
    for (int mt = 0; mt < 2; mt++) {
#pragma unroll
      for (int sc = 0; sc < 4; sc++) {
        floatx4 s4 = stf[mt][sc];
        float p0 = ex2(s4[0]);
        float p1 = ex2(s4[1]);
        float p2 = ex2(s4[2]);
        float p3 = ex2(s4[3]);
        *(uint2*)&Plds[wave][mt * 16 + l15][sc * 16 + quad * 4] =
            make_uint2(cvtpk(p0, p1), cvtpk(p2, p3));
      }
    }
    asm volatile("s_waitcnt lgkmcnt(0)" ::: "memory");
    __builtin_amdgcn_s_setprio(1);
#pragma unroll
    for (int sc2 = 0; sc2 < 2; sc2++) {
      bf16x8 pf[2];
#pragma unroll
      for (int mt = 0; mt < 2; mt++)
        pf[mt] = *(const bf16x8*)&Plds[wave][mt * 16 + l15][sc2 * 32 + quad * 8];
#pragma unroll
      for (int mt = 0; mt < 2; mt++)
        lacc[mt] = __builtin_amdgcn_mfma_f32_16x16x32_bf16(ones, pf[mt], lacc[mt], 0, 0, 0);
#pragma unroll
      for (int dt = 0; dt < 4; dt++) {
        const bf16x8* vr = (const bf16x8*)(vv + (dt * 16 + l15) * 64);
        bf16x8 vf = vr[(sc2 * 4 + quad) ^ sx];
#pragma unroll
        for (int mt = 0; mt < 2; mt++)
          o[mt][dt] = __builtin_amdgcn_mfma_f32_16x16x32_bf16(vf, pf[mt], o[mt][dt], 0, 0, 0);
      }
    }
    __builtin_amdgcn_s_setprio(0);
  }

#pragma unroll
  for (int mt = 0; mt < 2; mt++) {
    float inv = 1.0f / lacc[mt][0];  // every lane's reg0 = full row sum
    int row = (bh >> 4) * CTX + qbase + mt * 16 + l15;
    u16* orow = out + (size_t)row * DMODEL + (bh & 15) * 64;
#pragma unroll
    for (int dt = 0; dt < 4; dt++) {
      floatx4 v = o[mt][dt];
      *(u32*)(orow + dt * 16 + quad * 4) = cvtpk(v[0] * inv, v[1] * inv);
      *(u32*)(orow + dt * 16 + quad * 4 + 2) = cvtpk(v[2] * inv, v[3] * inv);
    }
  }
}

extern "C" void kernel_launch(void* const* d_in, const int* in_sizes, int n_in,
                              void* d_out, int out_size, void* d_ws, size_t ws_size,
                              hipStream_t stream) {
  const float* x  = (const float*)d_in[0];
  const float* Wq = (const float*)d_in[1];
  const float* Wk = (const float*)d_in[2];
  const float* Wv = (const float*)d_in[3];
  const float* W1 = (const float*)d_in[4];
  const float* b1 = (const float*)d_in[5];
  const float* W2 = (const float*)d_in[6];
  const float* b2 = (const float*)d_in[7];
  float* out = (float*)d_out;

  u16* ws    = (u16*)d_ws;
  u16* W2t   = ws;                              // [1024][4096]  8 MB
  u16* W1b   = W2t + (size_t)1024 * 4096;       // [1024][4096]  8 MB (bf16 W1)
  u16* Wft   = W1b + (size_t)1024 * 4096;       // [1024][1024]  2 MB
  float* bfv = (float*)(Wft + (size_t)1024 * 1024);  // [1024] f32
  float* bfp = bfv + 1024;                      // [32][1024] f32 128 KB
  u16* xb    = (u16*)(bfp + 32 * 1024);         // [8192][1024] 16 MB
  u16* Wqkvt = xb + (size_t)MROWS * 1024;       // [3072][1024]  6 MB
  u16* q     = Wqkvt + (size_t)3072 * 1024;     // [B*H][T][64] 16 MB
  u16* k     = q + (size_t)MROWS * 1024;        // [B*H][T][64] 16 MB
  u16* vt    = k + (size_t)MROWS * 1024;        // [B*H][64][T] 16 MB
  float* partials = (float*)(vt + (size_t)MROWS * 1024);  // [4][1M] f32 16 MB
  u16* att   = xb;                              // att aliases xb (dead post-QKV)

  // 1) all input conditioning + bias partials in ONE launch
  prep<<<19584, 256, 0, stream>>>(x, xb, W1, W1b, Wq, Wk, Wv, Wqkvt,
                                  W2, W2t, b1, bfp);
  // 2) QKV (blocks 0-767) + Wf split-K partials (blocks 768-895) in ONE launch
  gemm128<0><<<896, 512, 0, stream>>>(xb, Wqkvt, nullptr, q, k, vt,
                                      3072, 1024, 1024, W2t, W1b, partials);
  // 3) attention (y<16) + Wf reduce + bfv reduce (y==16) in ONE launch
  attn_mfma<<<dim3(64, 17), 256, 0, stream>>>(q, k, vt, att, partials, Wft,
                                              bfp, b2, bfv);
  // 4) fused FFN: out = relu(att @ Wf + bfv)
  gemm128<2><<<256, 512, 0, stream>>>(att, Wft, bfv, out, nullptr, nullptr,
                                      1024, 1024, 1024, nullptr, nullptr, nullptr);
}